// Round 1
// baseline (4985.475 us; speedup 1.0000x reference)
//
#include <hip/hip_runtime.h>
#include <hip/hip_bf16.h>
#include <hip/hip_cooperative_groups.h>

namespace cg = cooperative_groups;

typedef __bf16  bf16x8 __attribute__((ext_vector_type(8)));
typedef float   f32x4  __attribute__((ext_vector_type(4)));
typedef unsigned short usv8 __attribute__((ext_vector_type(8)));

#define GLOAD16(gptr, lptr) \
  __builtin_amdgcn_global_load_lds((const __attribute__((address_space(1))) void*)(gptr), \
                                   (__attribute__((address_space(3))) void*)(lptr), 16, 0, 0)

__device__ __forceinline__ float sigm(float x)  { return 1.0f / (1.0f + __expf(-x)); }
__device__ __forceinline__ float tanhp(float x) { return 2.0f / (1.0f + __expf(-2.0f * x)) - 1.0f; }

// Dimensions
#define TSTEPS 80
#define BATCH  512
#define EDIM   256
#define HDIM   512
#define NQ     2048   // 4*H (gate-interleaved)
#define K1     768    // H + E  (z1 = [h1, x] @ [U1p; W1p])
#define K2     1024   // H + H  (z2 = [h1, h2] @ [W2p; U2p])

struct Params {
  const __hip_bfloat16* Wz1t;   // [2048][768]  bf16, [N][K]
  const __hip_bfloat16* Wz2t;   // [2048][1024] bf16, [N][K]
  const float* bz1;             // [2048] permuted
  const float* bz2;             // [2048] permuted
  const __hip_bfloat16* Xall;   // [80][512][256] bf16
  __hip_bfloat16* h1b0; __hip_bfloat16* h1b1;   // [512][512] bf16 ping-pong
  __hip_bfloat16* h2b0; __hip_bfloat16* h2b1;
  float* c1; float* c2;                          // [512][512] fp32
  const float* Wfc; const float* bfc;
  float* out;                                    // [512] fp32
};

// ---------------- prep kernels ----------------

__global__ __launch_bounds__(256) void prep_weights(
    const float* __restrict__ W1, const float* __restrict__ U1, const float* __restrict__ b1,
    const float* __restrict__ W2, const float* __restrict__ U2, const float* __restrict__ b2,
    __hip_bfloat16* __restrict__ Wz1t, __hip_bfloat16* __restrict__ Wz2t,
    float* __restrict__ bz1, float* __restrict__ bz2) {
  long idx = (long)blockIdx.x * 256 + threadIdx.x;
  const long n1 = 2048L * 768, n2 = 2048L * 1024;
  if (idx < n1) {
    int n = (int)(idx / 768), k = (int)(idx % 768);
    int col = (n & 3) * 512 + (n >> 2);           // permuted col' = 4*j+g -> orig g*512+j
    float v = (k < 512) ? U1[(size_t)k * 2048 + col] : W1[(size_t)(k - 512) * 2048 + col];
    Wz1t[idx] = __float2bfloat16(v);
  } else if (idx < n1 + n2) {
    long r = idx - n1;
    int n = (int)(r / 1024), k = (int)(r % 1024);
    int col = (n & 3) * 512 + (n >> 2);
    float v = (k < 512) ? W2[(size_t)k * 2048 + col] : U2[(size_t)(k - 512) * 2048 + col];
    Wz2t[r] = __float2bfloat16(v);
  } else if (idx < n1 + n2 + 2048) {
    int n = (int)(idx - (n1 + n2));
    bz1[n] = b1[(n & 3) * 512 + (n >> 2)];
  } else if (idx < n1 + n2 + 4096) {
    int n = (int)(idx - (n1 + n2 + 2048));
    bz2[n] = b2[(n & 3) * 512 + (n >> 2)];
  }
}

__global__ __launch_bounds__(256) void prep_gather(
    const int* __restrict__ tokens, const float* __restrict__ emb,
    __hip_bfloat16* __restrict__ Xall) {
  int idx = blockIdx.x * 256 + threadIdx.x;   // 2,621,440 threads, 4 elems each
  int e  = (idx & 63) * 4;
  int rb = idx >> 6;            // t*512 + b
  int t  = rb >> 9;
  int b  = rb & 511;
  int tok = tokens[b * TSTEPS + t];
  const float4 v = *(const float4*)&emb[(size_t)tok * EDIM + e];
  __hip_bfloat16* o = Xall + (size_t)rb * EDIM + e;
  o[0] = __float2bfloat16(v.x); o[1] = __float2bfloat16(v.y);
  o[2] = __float2bfloat16(v.z); o[3] = __float2bfloat16(v.w);
}

__global__ __launch_bounds__(256) void zero_ws(float4* p, int n) {
  int i = blockIdx.x * 256 + threadIdx.x;
  if (i < n) p[i] = make_float4(0.f, 0.f, 0.f, 0.f);
}

// ---------------- main sequential kernel ----------------
// Grid: 256 blocks x 256 threads. Blocks 0..127: z2 GEMM (4x32 tiles of 128x64).
// Blocks 128..255: z1 GEMM. One grid.sync per phase; phase p computes
// z2[p] (h2[p],c2[p]) and z1[p+1] (h1[p+1],c1[p+1]).

__global__ __launch_bounds__(256) void lstm_seq(Params p) {
  const int tid  = threadIdx.x;
  const int lane = tid & 63;
  const int w    = tid >> 6;        // wave 0..3
  const int wm   = w >> 1, wn = w & 1;
  const int q    = lane >> 4;       // quad 0..3
  const int m16  = lane & 15;

  const bool z2role = (blockIdx.x < 128);
  const int lid = blockIdx.x & 127;
  const int m0  = (lid >> 5) * 128;   // batch tile base
  const int n0  = (lid & 31) * 64;    // permuted-gate column base

  __shared__ __align__(16) __hip_bfloat16 As[2][128 * 32];
  __shared__ __align__(16) __hip_bfloat16 Bs[2][64 * 32];
  __shared__ float zb[128][65];

  cg::grid_group grid = cg::this_grid();

  const __hip_bfloat16* Bmat = z2role ? p.Wz2t : p.Wz1t;
  const int strideB  = z2role ? K2 : K1;
  const int nchunks  = z2role ? (K2 / 32) : (K1 / 32);
  const float* bias  = z2role ? p.bz2 : p.bz1;
  float* cptr        = z2role ? p.c2 : p.c1;

  for (int ph = -1; ph < TSTEPS; ++ph) {
    const bool active = z2role ? (ph >= 0) : (ph < TSTEPS - 1);
    if (active) {
      const __hip_bfloat16* A0 = (ph & 1) ? p.h1b1 : p.h1b0;   // h1[ph]
      const __hip_bfloat16* A1;
      int s1;
      if (z2role) { A1 = ((ph + 1) & 1) ? p.h2b1 : p.h2b0; s1 = 512; }  // h2[ph-1]
      else        { A1 = p.Xall + (size_t)(ph + 1) * BATCH * EDIM; s1 = 256; }

      f32x4 acc[4][2];
#pragma unroll
      for (int i = 0; i < 4; ++i)
#pragma unroll
        for (int j = 0; j < 2; ++j) acc[i][j] = (f32x4){0.f, 0.f, 0.f, 0.f};

      auto stage = [&](int kc, int bsel) {
        const int kk = kc * 32;
        const __hip_bfloat16* Ab; int sA, kloc;
        if (kk < 512) { Ab = A0; sA = 512; kloc = kk; }
        else          { Ab = A1; sA = s1;  kloc = kk - 512; }
#pragma unroll
        for (int rd = 0; rd < 2; ++rd) {           // A: 128x32 = 512 granules
          int g   = (rd * 4 + w) * 64 + lane;
          int row = g >> 2;
          int gc  = (g & 3) ^ ((row >> 1) & 3);    // XOR swizzle
          GLOAD16(Ab + (size_t)(m0 + row) * sA + kloc + gc * 8, &As[bsel][g * 8]);
        }
        {                                          // B: 64x32 = 256 granules
          int g   = w * 64 + lane;
          int row = g >> 2;
          int gc  = (g & 3) ^ ((row >> 1) & 3);
          GLOAD16(Bmat + (size_t)(n0 + row) * strideB + kk + gc * 8, &Bs[bsel][g * 8]);
        }
      };

      auto compute = [&](int bsel) {
        bf16x8 af[4], bfr[2];
#pragma unroll
        for (int mi = 0; mi < 4; ++mi) {
          int r  = wm * 64 + mi * 16 + m16;
          int sw = q ^ ((r >> 1) & 3);
          af[mi] = *(const bf16x8*)&As[bsel][r * 32 + sw * 8];
        }
#pragma unroll
        for (int ni = 0; ni < 2; ++ni) {
          int r  = wn * 32 + ni * 16 + m16;
          int sw = q ^ ((r >> 1) & 3);
          bfr[ni] = *(const bf16x8*)&Bs[bsel][r * 32 + sw * 8];
        }
#pragma unroll
        for (int mi = 0; mi < 4; ++mi)
#pragma unroll
          for (int ni = 0; ni < 2; ++ni)
            acc[mi][ni] = __builtin_amdgcn_mfma_f32_16x16x32_bf16(af[mi], bfr[ni], acc[mi][ni], 0, 0, 0);
      };

      stage(0, 0);
      for (int kc = 0; kc < nchunks; ++kc) {
        __syncthreads();                            // drains vmcnt -> buf[kc&1] ready
        if (kc + 1 < nchunks) stage(kc + 1, (kc + 1) & 1);
        compute(kc & 1);
      }

      // epilogue: acc -> LDS -> gates
#pragma unroll
      for (int mi = 0; mi < 4; ++mi)
#pragma unroll
        for (int ni = 0; ni < 2; ++ni)
#pragma unroll
          for (int r = 0; r < 4; ++r)
            zb[wm * 64 + mi * 16 + q * 4 + r][wn * 32 + ni * 16 + m16] = acc[mi][ni][r];
      __syncthreads();

      __hip_bfloat16* hout = z2role ? ((ph & 1) ? p.h2b1 : p.h2b0)            // h2[ph]
                                    : (((ph + 1) & 1) ? p.h1b1 : p.h1b0);     // h1[ph+1]
      const int trow = tid & 127;
      const int gsel = tid >> 7;
      const int bb = m0 + trow;
#pragma unroll
      for (int gg = 0; gg < 2; ++gg) {
        int grp = gsel * 2 + gg;     // 0..3 -> 4 units each
#pragma unroll
        for (int u = 0; u < 4; ++u) {
          int jl = grp * 4 + u;      // local unit 0..15
          int cb = jl * 4;
          float zi = zb[trow][cb + 0] + bias[n0 + cb + 0];
          float zf = zb[trow][cb + 1] + bias[n0 + cb + 1];
          float zg = zb[trow][cb + 2] + bias[n0 + cb + 2];
          float zo = zb[trow][cb + 3] + bias[n0 + cb + 3];
          int j = (n0 >> 2) + jl;
          float co = cptr[(size_t)bb * HDIM + j];
          float cn = sigm(zf) * co + sigm(zi) * tanhp(zg);
          cptr[(size_t)bb * HDIM + j] = cn;
          hout[(size_t)bb * HDIM + j] = __float2bfloat16(sigm(zo) * tanhp(cn));
        }
      }
    }
    grid.sync();
  }

  // final: out = sigmoid(h2[T-1] @ Wfc + bfc); h2[79] is in h2b1 (79&1==1)
  if (blockIdx.x == 0) {
    const __hip_bfloat16* hf = p.h2b1;
    for (int b = tid; b < BATCH; b += 256) {
      float s = p.bfc[0];
      const usv8* hp = (const usv8*)(hf + (size_t)b * HDIM);
#pragma unroll 4
      for (int k8 = 0; k8 < HDIM / 8; ++k8) {
        usv8 hv = hp[k8];
#pragma unroll
        for (int u = 0; u < 8; ++u) {
          union { unsigned int ui; float f; } cv;
          cv.ui = ((unsigned int)hv[u]) << 16;
          s += cv.f * p.Wfc[k8 * 8 + u];
        }
      }
      p.out[b] = sigm(s);
    }
  }
}

// ---------------- host launcher ----------------

extern "C" void kernel_launch(void* const* d_in, const int* in_sizes, int n_in,
                              void* d_out, int out_size, void* d_ws, size_t ws_size,
                              hipStream_t stream) {
  const int*   tokens = (const int*)d_in[0];
  const float* emb = (const float*)d_in[1];
  const float* W1  = (const float*)d_in[2];
  const float* U1  = (const float*)d_in[3];
  const float* b1  = (const float*)d_in[4];
  const float* W2  = (const float*)d_in[5];
  const float* U2  = (const float*)d_in[6];
  const float* b2  = (const float*)d_in[7];
  const float* Wfc = (const float*)d_in[8];
  const float* bfc = (const float*)d_in[9];

  char* ws = (char*)d_ws;
  size_t off = 0;
  auto alloc = [&](size_t bytes) {
    char* r = ws + off;
    off += (bytes + 255) & ~(size_t)255;
    return r;
  };
  __hip_bfloat16* Wz1t = (__hip_bfloat16*)alloc(2048UL * 768 * 2);
  __hip_bfloat16* Wz2t = (__hip_bfloat16*)alloc(2048UL * 1024 * 2);
  float* bz1 = (float*)alloc(2048 * 4);
  float* bz2 = (float*)alloc(2048 * 4);
  __hip_bfloat16* Xall = (__hip_bfloat16*)alloc((size_t)TSTEPS * BATCH * EDIM * 2);
  char* state = alloc(4UL * 1024 * 1024);   // zeroed block
  __hip_bfloat16* h1b0 = (__hip_bfloat16*)(state);
  __hip_bfloat16* h1b1 = (__hip_bfloat16*)(state + 512 * 1024);
  __hip_bfloat16* h2b0 = (__hip_bfloat16*)(state + 1024 * 1024);
  __hip_bfloat16* h2b1 = (__hip_bfloat16*)(state + 1536 * 1024);
  float* c1 = (float*)(state + 2048 * 1024);
  float* c2 = (float*)(state + 3072 * 1024);

  prep_weights<<<dim3(14352), dim3(256), 0, stream>>>(W1, U1, b1, W2, U2, b2, Wz1t, Wz2t, bz1, bz2);
  prep_gather<<<dim3(10240), dim3(256), 0, stream>>>(tokens, emb, Xall);
  zero_ws<<<dim3(1024), dim3(256), 0, stream>>>((float4*)state, 262144);

  Params prm;
  prm.Wz1t = Wz1t; prm.Wz2t = Wz2t; prm.bz1 = bz1; prm.bz2 = bz2;
  prm.Xall = Xall;
  prm.h1b0 = h1b0; prm.h1b1 = h1b1; prm.h2b0 = h2b0; prm.h2b1 = h2b1;
  prm.c1 = c1; prm.c2 = c2;
  prm.Wfc = Wfc; prm.bfc = bfc;
  prm.out = (float*)d_out;

  void* args[] = {&prm};
  hipLaunchCooperativeKernel((const void*)lstm_seq, dim3(256), dim3(256), args, 0, stream);
}

// Round 2
// 2993.670 us; speedup vs baseline: 1.6653x; 1.6653x over previous
//
#include <hip/hip_runtime.h>
#include <hip/hip_bf16.h>
#include <hip/hip_cooperative_groups.h>

namespace cg = cooperative_groups;

typedef __bf16  bf16x8 __attribute__((ext_vector_type(8)));
typedef float   f32x4  __attribute__((ext_vector_type(4)));

#define GLOAD16(gptr, lptr) \
  __builtin_amdgcn_global_load_lds((const __attribute__((address_space(1))) void*)(gptr), \
                                   (__attribute__((address_space(3))) void*)(lptr), 16, 0, 0)

#define WAIT_VM4   asm volatile("s_waitcnt vmcnt(4)" ::: "memory")
#define WAIT_VM2   asm volatile("s_waitcnt vmcnt(2)" ::: "memory")
#define WAIT_VM0   asm volatile("s_waitcnt vmcnt(0)" ::: "memory")
#define WAIT_LGKM0 asm volatile("s_waitcnt lgkmcnt(0)" ::: "memory")

__device__ __forceinline__ float sigm(float x)  { return 1.0f / (1.0f + __expf(-x)); }
__device__ __forceinline__ float tanhp(float x) { return 2.0f / (1.0f + __expf(-2.0f * x)) - 1.0f; }

#define TSTEPS 80
#define BATCH  512
#define EDIM   256
#define HDIM   512
#define K2     1024
#define K1     768
#define KP2    (K2 + 8)
#define KP1    (K1 + 8)
// LDS: Bs (64 x KP, bf16) + 3-deep A ring (128x32 bf16 = 8192B each)
#define LDS_BYTES (64 * KP2 * 2 + 3 * 8192)

struct Params {
  const __hip_bfloat16* Wz1t;   // [2048][768]  bf16, [N'][K], col-permuted
  const __hip_bfloat16* Wz2t;   // [2048][1024]
  const float* bz1;             // [2048] permuted
  const float* bz2;
  const __hip_bfloat16* Xall;   // [80][512][256] bf16
  __hip_bfloat16* h1b0; __hip_bfloat16* h1b1;   // [512][512] bf16 ping-pong
  __hip_bfloat16* h2b0; __hip_bfloat16* h2b1;
  const float* Wfc; const float* bfc;
  float* out;
};

// ---------------- prep kernels ----------------
// permuted column: n' = ntile*64 + gate*16 + u  (ntile = j>>4, u = j&15)
// inverse: ntile = n'>>6, gate = (n'>>4)&3, u = n'&15, col_orig = gate*512 + ntile*16 + u

__global__ __launch_bounds__(256) void prep_weights(
    const float* __restrict__ W1, const float* __restrict__ U1, const float* __restrict__ b1,
    const float* __restrict__ W2, const float* __restrict__ U2, const float* __restrict__ b2,
    __hip_bfloat16* __restrict__ Wz1t, __hip_bfloat16* __restrict__ Wz2t,
    float* __restrict__ bz1, float* __restrict__ bz2) {
  long idx = (long)blockIdx.x * 256 + threadIdx.x;
  const long n1 = 2048L * K1, n2 = 2048L * K2;
  if (idx < n1) {
    int n = (int)(idx / K1), k = (int)(idx % K1);
    int col = ((n >> 4) & 3) * 512 + (n >> 6) * 16 + (n & 15);
    float v = (k < 512) ? U1[(size_t)k * 2048 + col] : W1[(size_t)(k - 512) * 2048 + col];
    Wz1t[idx] = __float2bfloat16(v);
  } else if (idx < n1 + n2) {
    long r = idx - n1;
    int n = (int)(r / K2), k = (int)(r % K2);
    int col = ((n >> 4) & 3) * 512 + (n >> 6) * 16 + (n & 15);
    float v = (k < 512) ? W2[(size_t)k * 2048 + col] : U2[(size_t)(k - 512) * 2048 + col];
    Wz2t[r] = __float2bfloat16(v);
  } else if (idx < n1 + n2 + 2048) {
    int n = (int)(idx - (n1 + n2));
    bz1[n] = b1[((n >> 4) & 3) * 512 + (n >> 6) * 16 + (n & 15)];
  } else if (idx < n1 + n2 + 4096) {
    int n = (int)(idx - (n1 + n2 + 2048));
    bz2[n] = b2[((n >> 4) & 3) * 512 + (n >> 6) * 16 + (n & 15)];
  }
}

__global__ __launch_bounds__(256) void prep_gather(
    const int* __restrict__ tokens, const float* __restrict__ emb,
    __hip_bfloat16* __restrict__ Xall) {
  int idx = blockIdx.x * 256 + threadIdx.x;
  int e  = (idx & 63) * 4;
  int rb = idx >> 6;            // t*512 + b
  int t  = rb >> 9;
  int b  = rb & 511;
  int tok = tokens[b * TSTEPS + t];
  const float4 v = *(const float4*)&emb[(size_t)tok * EDIM + e];
  __hip_bfloat16* o = Xall + (size_t)rb * EDIM + e;
  o[0] = __float2bfloat16(v.x); o[1] = __float2bfloat16(v.y);
  o[2] = __float2bfloat16(v.z); o[3] = __float2bfloat16(v.w);
}

__global__ __launch_bounds__(256) void zero_ws(float4* p, int n) {
  int i = blockIdx.x * 256 + threadIdx.x;
  if (i < n) p[i] = make_float4(0.f, 0.f, 0.f, 0.f);
}

// ---------------- main sequential kernel ----------------
// 256 blocks x 256 threads, 1 block/CU (LDS-bound). Blocks 0..127: z2 GEMM;
// 128..255: z1 GEMM. m-tile = blockIdx&3 (aligns with XCD = blockIdx%8 for L2
// locality). Each block: 128x64 tile, wave w owns rows [w*32, w*32+32) —
// stages and reads ONLY its own rows -> no intra-block barrier in K-loop.
// Weights persistent in LDS; cell state in registers; bias folded into acc.

__global__ __launch_bounds__(256) void lstm_seq(Params p) {
  extern __shared__ char smem[];
  const int tid  = threadIdx.x;
  const int lane = tid & 63;
  const int w    = tid >> 6;
  const int q    = lane >> 4;
  const int m16  = lane & 15;

  const bool z2 = (blockIdx.x < 128);
  const int idx = z2 ? blockIdx.x : (blockIdx.x - 128);
  const int m0    = (idx & 3) * 128;
  const int ntile = idx >> 2;            // 0..31
  const int n0    = ntile * 64;
  const int K  = z2 ? K2 : K1;
  const int KP = z2 ? KP2 : KP1;
  const int nc = K / 32;

  __hip_bfloat16* Bs   = (__hip_bfloat16*)smem;
  __hip_bfloat16* ring = (__hip_bfloat16*)(smem + (size_t)64 * KP * 2);

  // ---- one-time: load persistent B tile into padded LDS ----
  const __hip_bfloat16* Bg = (z2 ? p.Wz2t : p.Wz1t) + (size_t)n0 * K;
  if (z2) {
    for (int g0 = tid; g0 < 64 * (K2 / 8); g0 += 256) {
      int r = g0 >> 7, c8 = g0 & 127;
      *(bf16x8*)(Bs + r * KP2 + c8 * 8) = *(const bf16x8*)(Bg + (size_t)r * K2 + c8 * 8);
    }
  } else {
    for (int g0 = tid; g0 < 64 * (K1 / 8); g0 += 256) {
      int r = g0 / 96, c8 = g0 - r * 96;
      *(bf16x8*)(Bs + r * KP1 + c8 * 8) = *(const bf16x8*)(Bg + (size_t)r * K1 + c8 * 8);
    }
  }
  const float* bias = z2 ? p.bz2 : p.bz1;
  float bz[4];
#pragma unroll
  for (int g = 0; g < 4; ++g) bz[g] = bias[n0 + g * 16 + m16];

  float cst[2][4] = {{0.f,0.f,0.f,0.f},{0.f,0.f,0.f,0.f}};   // cell state, in regs for all 80 steps
  __syncthreads();

  cg::grid_group grid = cg::this_grid();

  for (int ph = -1; ph < TSTEPS; ++ph) {
    const bool active = z2 ? (ph >= 0) : (ph < TSTEPS - 1);
    if (active) {
      const __hip_bfloat16* A0 = (ph & 1) ? p.h1b1 : p.h1b0;     // h1[ph]
      const __hip_bfloat16* A1; int s1;
      if (z2) { A1 = ((ph + 1) & 1) ? p.h2b1 : p.h2b0; s1 = 512; }   // h2[ph-1]
      else    { A1 = p.Xall + (size_t)(ph + 1) * BATCH * EDIM; s1 = 256; }

      // stage chunk kc: wave w loads its own 32 rows (128 granules, 2 insts)
      auto stage = [&](int kc) {
        const int slot = kc % 3;
        const int kk = kc * 32;
        const __hip_bfloat16* Ab; int sA, kloc;
        if (kk < 512) { Ab = A0; sA = 512; kloc = kk; }
        else          { Ab = A1; sA = s1;  kloc = kk - 512; }
#pragma unroll
        for (int it = 0; it < 2; ++it) {
          const int gbase = w * 128 + it * 64;
          const int g   = gbase + lane;
          const int row = g >> 2;
          const int gc  = (g & 3) ^ ((row >> 1) & 3);     // XOR swizzle
          GLOAD16(Ab + (size_t)(m0 + row) * sA + kloc + gc * 8,
                  ring + (size_t)slot * 4096 + gbase * 8);
        }
      };

      f32x4 acc[2][4];
#pragma unroll
      for (int mi = 0; mi < 2; ++mi)
#pragma unroll
        for (int g = 0; g < 4; ++g)
          acc[mi][g] = (f32x4){bz[g], bz[g], bz[g], bz[g]};

      WAIT_LGKM0;                     // prior-phase ds_reads retired before restage
      stage(0); stage(1); stage(2);

      for (int kc = 0; kc < nc; ++kc) {
        if      (kc <= nc - 3) WAIT_VM4;   // chunk kc resident (2 newer chunks in flight)
        else if (kc == nc - 2) WAIT_VM2;
        else                   WAIT_VM0;
        const int slot = kc % 3;
        bf16x8 af[2], bfr[4];
#pragma unroll
        for (int mi = 0; mi < 2; ++mi) {
          const int row = w * 32 + mi * 16 + m16;
          const int sw  = q ^ ((row >> 1) & 3);
          af[mi] = *(const bf16x8*)(ring + slot * 4096 + row * 32 + sw * 8);
        }
#pragma unroll
        for (int g = 0; g < 4; ++g)
          bfr[g] = *(const bf16x8*)(Bs + (g * 16 + m16) * KP + kc * 32 + q * 8);
        WAIT_LGKM0;                   // frags in regs; ring slot (kc%3) now free
        if (kc + 3 < nc) stage(kc + 3);
#pragma unroll
        for (int mi = 0; mi < 2; ++mi)
#pragma unroll
          for (int g = 0; g < 4; ++g)
            acc[mi][g] = __builtin_amdgcn_mfma_f32_16x16x32_bf16(af[mi], bfr[g], acc[mi][g], 0, 0, 0);
      }

      // in-register epilogue: lane owns unit j = ntile*16+m16, 8 rows
      __hip_bfloat16* hout = z2 ? ((ph & 1) ? p.h2b1 : p.h2b0)            // h2[ph]
                                : (((ph + 1) & 1) ? p.h1b1 : p.h1b0);     // h1[ph+1]
      const int j = ntile * 16 + m16;
#pragma unroll
      for (int mi = 0; mi < 2; ++mi)
#pragma unroll
        for (int rr = 0; rr < 4; ++rr) {
          const float zi = acc[mi][0][rr], zf = acc[mi][1][rr];
          const float zg = acc[mi][2][rr], zo = acc[mi][3][rr];
          const float cn = sigm(zf) * cst[mi][rr] + sigm(zi) * tanhp(zg);
          cst[mi][rr] = cn;
          const int row = m0 + w * 32 + mi * 16 + q * 4 + rr;
          hout[(size_t)row * HDIM + j] = __float2bfloat16(sigm(zo) * tanhp(cn));
        }
    }
    grid.sync();
  }

  // final FC: block b -> rows {2b, 2b+1}; wave 0/1 one row each
  if (w < 2) {
    const int row = blockIdx.x * 2 + w;
    const __hip_bfloat16* hf = p.h2b1 + (size_t)row * HDIM;   // h2[79] (79&1 -> b1)
    bf16x8 hv = *(const bf16x8*)(hf + lane * 8);
    float sum = 0.f;
#pragma unroll
    for (int u = 0; u < 8; ++u) sum += (float)hv[u] * p.Wfc[lane * 8 + u];
#pragma unroll
    for (int o = 32; o > 0; o >>= 1) sum += __shfl_down(sum, o, 64);
    if (lane == 0) p.out[row] = sigm(sum + p.bfc[0]);
  }
}

// ---------------- host launcher ----------------

extern "C" void kernel_launch(void* const* d_in, const int* in_sizes, int n_in,
                              void* d_out, int out_size, void* d_ws, size_t ws_size,
                              hipStream_t stream) {
  const int*   tokens = (const int*)d_in[0];
  const float* emb = (const float*)d_in[1];
  const float* W1  = (const float*)d_in[2];
  const float* U1  = (const float*)d_in[3];
  const float* b1  = (const float*)d_in[4];
  const float* W2  = (const float*)d_in[5];
  const float* U2  = (const float*)d_in[6];
  const float* b2  = (const float*)d_in[7];
  const float* Wfc = (const float*)d_in[8];
  const float* bfc = (const float*)d_in[9];

  char* ws = (char*)d_ws;
  size_t off = 0;
  auto alloc = [&](size_t bytes) {
    char* r = ws + off;
    off += (bytes + 255) & ~(size_t)255;
    return r;
  };
  __hip_bfloat16* Wz1t = (__hip_bfloat16*)alloc(2048UL * K1 * 2);
  __hip_bfloat16* Wz2t = (__hip_bfloat16*)alloc(2048UL * K2 * 2);
  float* bz1 = (float*)alloc(2048 * 4);
  float* bz2 = (float*)alloc(2048 * 4);
  __hip_bfloat16* Xall = (__hip_bfloat16*)alloc((size_t)TSTEPS * BATCH * EDIM * 2);
  char* state = alloc(2UL * 1024 * 1024);   // 4 h-buffers, zeroed
  __hip_bfloat16* h1b0 = (__hip_bfloat16*)(state);
  __hip_bfloat16* h1b1 = (__hip_bfloat16*)(state + 512 * 1024);
  __hip_bfloat16* h2b0 = (__hip_bfloat16*)(state + 1024 * 1024);
  __hip_bfloat16* h2b1 = (__hip_bfloat16*)(state + 1536 * 1024);

  prep_weights<<<dim3(14352), dim3(256), 0, stream>>>(W1, U1, b1, W2, U2, b2, Wz1t, Wz2t, bz1, bz2);
  prep_gather<<<dim3(10240), dim3(256), 0, stream>>>(tokens, emb, Xall);
  zero_ws<<<dim3(512), dim3(256), 0, stream>>>((float4*)state, 131072);

  static int lds_set = 0;
  if (!lds_set) {
    hipFuncSetAttribute((const void*)lstm_seq,
                        hipFuncAttributeMaxDynamicSharedMemorySize, LDS_BYTES);
    lds_set = 1;
  }

  Params prm;
  prm.Wz1t = Wz1t; prm.Wz2t = Wz2t; prm.bz1 = bz1; prm.bz2 = bz2;
  prm.Xall = Xall;
  prm.h1b0 = h1b0; prm.h1b1 = h1b1; prm.h2b0 = h2b0; prm.h2b1 = h2b1;
  prm.Wfc = Wfc; prm.bfc = bfc;
  prm.out = (float*)d_out;

  void* args[] = {&prm};
  hipLaunchCooperativeKernel((const void*)lstm_seq, dim3(256), dim3(256), args, LDS_BYTES, stream);
}

// Round 3
// 1153.632 us; speedup vs baseline: 4.3215x; 2.5950x over previous
//
#include <hip/hip_runtime.h>
#include <hip/hip_bf16.h>

typedef __bf16  bf16x8 __attribute__((ext_vector_type(8)));
typedef float   f32x4  __attribute__((ext_vector_type(4)));

// global->LDS async, 16B/lane. _C = cached (read-only streams), _H = coherent
// (SC0|SC1 = bypass L1/L2, read at LLC which is memory-side & XCD-coherent).
#define GLOAD16_C(gptr, lptr) \
  __builtin_amdgcn_global_load_lds((const __attribute__((address_space(1))) void*)(gptr), \
                                   (__attribute__((address_space(3))) void*)(lptr), 16, 0, 0)
#define GLOAD16_H(gptr, lptr) \
  __builtin_amdgcn_global_load_lds((const __attribute__((address_space(1))) void*)(gptr), \
                                   (__attribute__((address_space(3))) void*)(lptr), 16, 0, 0x11)

#define WAIT_VM4   asm volatile("s_waitcnt vmcnt(4)" ::: "memory")
#define WAIT_VM2   asm volatile("s_waitcnt vmcnt(2)" ::: "memory")
#define WAIT_VM0   asm volatile("s_waitcnt vmcnt(0)" ::: "memory")
#define WAIT_LGKM0 asm volatile("s_waitcnt lgkmcnt(0)" ::: "memory")

__device__ __forceinline__ float sigm(float x)  { return 1.0f / (1.0f + __expf(-x)); }
__device__ __forceinline__ float tanhp(float x) { return 2.0f / (1.0f + __expf(-2.0f * x)) - 1.0f; }

// coherent (LLC) scalar load, bypasses L1/L2
__device__ __forceinline__ unsigned int coh_load(const unsigned int* p) {
  unsigned int v;
  asm volatile("global_load_dword %0, %1, off sc0 sc1\n\ts_waitcnt vmcnt(0)"
               : "=v"(v) : "v"(p) : "memory");
  return v;
}
// coherent bf16 store (write-through to LLC; visible device-wide at vmcnt(0))
__device__ __forceinline__ void coh_store_bf16(__hip_bfloat16* p, float x) {
  __hip_bfloat16 hv = __float2bfloat16(x);
  unsigned int b = (unsigned int)*(unsigned short*)&hv;
  asm volatile("global_store_short %0, %1, off sc0 sc1" :: "v"(p), "v"(b) : "memory");
}

#define TSTEPS 80
#define BATCH  512
#define EDIM   256
#define HDIM   512
#define K2     1024
#define K1     768
#define KP2    (K2 + 8)
#define KP1    (K1 + 8)
#define LDS_BYTES (64 * KP2 * 2 + 3 * 8192)

struct Params {
  const __hip_bfloat16* Wz1t;   // [2048][768]  bf16, [N'][K], col-permuted
  const __hip_bfloat16* Wz2t;   // [2048][1024]
  const float* bz1;             // [2048] permuted
  const float* bz2;
  const __hip_bfloat16* Xall;   // [80][512][256] bf16
  __hip_bfloat16* h1b0; __hip_bfloat16* h1b1;   // [512][512] bf16 ping-pong
  __hip_bfloat16* h2b0; __hip_bfloat16* h2b1;
  unsigned int* cnt;            // 4 group barrier counters, 128B apart
  const float* Wfc; const float* bfc;
  float* out;
};

// ---------------- prep kernels ----------------
// permuted column: n' = ntile*64 + gate*16 + u  (ntile = j>>4, u = j&15)

__global__ __launch_bounds__(256) void prep_weights(
    const float* __restrict__ W1, const float* __restrict__ U1, const float* __restrict__ b1,
    const float* __restrict__ W2, const float* __restrict__ U2, const float* __restrict__ b2,
    __hip_bfloat16* __restrict__ Wz1t, __hip_bfloat16* __restrict__ Wz2t,
    float* __restrict__ bz1, float* __restrict__ bz2) {
  long idx = (long)blockIdx.x * 256 + threadIdx.x;
  const long n1 = 2048L * K1, n2 = 2048L * K2;
  if (idx < n1) {
    int n = (int)(idx / K1), k = (int)(idx % K1);
    int col = ((n >> 4) & 3) * 512 + (n >> 6) * 16 + (n & 15);
    float v = (k < 512) ? U1[(size_t)k * 2048 + col] : W1[(size_t)(k - 512) * 2048 + col];
    Wz1t[idx] = __float2bfloat16(v);
  } else if (idx < n1 + n2) {
    long r = idx - n1;
    int n = (int)(r / K2), k = (int)(r % K2);
    int col = ((n >> 4) & 3) * 512 + (n >> 6) * 16 + (n & 15);
    float v = (k < 512) ? W2[(size_t)k * 2048 + col] : U2[(size_t)(k - 512) * 2048 + col];
    Wz2t[r] = __float2bfloat16(v);
  } else if (idx < n1 + n2 + 2048) {
    int n = (int)(idx - (n1 + n2));
    bz1[n] = b1[((n >> 4) & 3) * 512 + (n >> 6) * 16 + (n & 15)];
  } else if (idx < n1 + n2 + 4096) {
    int n = (int)(idx - (n1 + n2 + 2048));
    bz2[n] = b2[((n >> 4) & 3) * 512 + (n >> 6) * 16 + (n & 15)];
  }
}

__global__ __launch_bounds__(256) void prep_gather(
    const int* __restrict__ tokens, const float* __restrict__ emb,
    __hip_bfloat16* __restrict__ Xall) {
  int idx = blockIdx.x * 256 + threadIdx.x;
  int e  = (idx & 63) * 4;
  int rb = idx >> 6;            // t*512 + b
  int t  = rb >> 9;
  int b  = rb & 511;
  int tok = tokens[b * TSTEPS + t];
  const float4 v = *(const float4*)&emb[(size_t)tok * EDIM + e];
  __hip_bfloat16* o = Xall + (size_t)rb * EDIM + e;
  o[0] = __float2bfloat16(v.x); o[1] = __float2bfloat16(v.y);
  o[2] = __float2bfloat16(v.z); o[3] = __float2bfloat16(v.w);
}

__global__ __launch_bounds__(256) void zero_ws(float4* p, int n) {
  int i = blockIdx.x * 256 + threadIdx.x;
  if (i < n) p[i] = make_float4(0.f, 0.f, 0.f, 0.f);
}

// ---------------- main sequential kernel ----------------
// 256 blocks x 256 threads, 1 block/CU. Block b: group g=(b>>1)&3 (m-tile,
// rows g*128..), role z2 if (b&1)==0, ntile = b>>3. blockIdx%8 = 2g+role
// pins each group to an XCD pair (L2/LLC locality heuristic only).
// All h traffic goes through the LLC (sc0|sc1); barriers are per-group
// 64-block atomic counters — NO cache flush, NO grid-wide sync.

__global__ __launch_bounds__(256) void lstm_seq(Params p) {
  extern __shared__ char smem[];
  const int tid  = threadIdx.x;
  const int lane = tid & 63;
  const int w    = tid >> 6;
  const int q    = lane >> 4;
  const int m16  = lane & 15;

  const int  grp   = (blockIdx.x >> 1) & 3;
  const bool z2    = ((blockIdx.x & 1) == 0);
  const int  ntile = blockIdx.x >> 3;          // 0..31
  const int  m0    = grp * 128;
  const int  n0    = ntile * 64;
  const int  K  = z2 ? K2 : K1;
  const int  KP = z2 ? KP2 : KP1;
  const int  nc = K / 32;
  unsigned int* cnt = p.cnt + grp * 32;

  __hip_bfloat16* Bs   = (__hip_bfloat16*)smem;
  __hip_bfloat16* ring = (__hip_bfloat16*)(smem + (size_t)64 * KP * 2);

  // one-time: persistent B tile into padded LDS
  const __hip_bfloat16* Bg = (z2 ? p.Wz2t : p.Wz1t) + (size_t)n0 * K;
  if (z2) {
    for (int g0 = tid; g0 < 64 * (K2 / 8); g0 += 256) {
      int r = g0 >> 7, c8 = g0 & 127;
      *(bf16x8*)(Bs + r * KP2 + c8 * 8) = *(const bf16x8*)(Bg + (size_t)r * K2 + c8 * 8);
    }
  } else {
    for (int g0 = tid; g0 < 64 * (K1 / 8); g0 += 256) {
      int r = g0 / 96, c8 = g0 - r * 96;
      *(bf16x8*)(Bs + r * KP1 + c8 * 8) = *(const bf16x8*)(Bg + (size_t)r * K1 + c8 * 8);
    }
  }
  const float* bias = z2 ? p.bz2 : p.bz1;
  float bz[4];
#pragma unroll
  for (int g = 0; g < 4; ++g) bz[g] = bias[n0 + g * 16 + m16];

  float cst[2][4] = {{0.f,0.f,0.f,0.f},{0.f,0.f,0.f,0.f}};   // cell state in regs
  __syncthreads();

  for (int ph = -1; ph < TSTEPS; ++ph) {
    if (z2 ? (ph >= 0) : (ph < TSTEPS - 1)) {
      const __hip_bfloat16* A0 = (ph & 1) ? p.h1b1 : p.h1b0;     // h1[ph]
      const __hip_bfloat16* A1;
      if (z2) A1 = ((ph + 1) & 1) ? p.h2b1 : p.h2b0;             // h2[ph-1]
      else    A1 = p.Xall + (size_t)(ph + 1) * BATCH * EDIM;     // x[ph+1]

      auto stage = [&](int kc) {
        const int slot = kc % 3;
        const int kk = kc * 32;
#pragma unroll
        for (int it = 0; it < 2; ++it) {
          const int gbase = w * 128 + it * 64;
          const int g   = gbase + lane;
          const int row = g >> 2;
          const int gc  = (g & 3) ^ ((row >> 1) & 3);     // XOR swizzle
          __hip_bfloat16* lp = ring + (size_t)slot * 4096 + gbase * 8;
          if (kk < 512) {
            GLOAD16_H(A0 + (size_t)(m0 + row) * 512 + kk + gc * 8, lp);
          } else if (z2) {
            GLOAD16_H(A1 + (size_t)(m0 + row) * 512 + (kk - 512) + gc * 8, lp);
          } else {
            GLOAD16_C(A1 + (size_t)(m0 + row) * 256 + (kk - 512) + gc * 8, lp);
          }
        }
      };

      f32x4 acc[2][4];
#pragma unroll
      for (int mi = 0; mi < 2; ++mi)
#pragma unroll
        for (int g = 0; g < 4; ++g)
          acc[mi][g] = (f32x4){bz[g], bz[g], bz[g], bz[g]};

      WAIT_LGKM0;                     // prior-phase ds_reads retired before restage
      stage(0); stage(1); stage(2);

      for (int kc = 0; kc < nc; ++kc) {
        if      (kc <= nc - 3) WAIT_VM4;
        else if (kc == nc - 2) WAIT_VM2;
        else                   WAIT_VM0;
        const int slot = kc % 3;
        bf16x8 af[2], bfr[4];
#pragma unroll
        for (int mi = 0; mi < 2; ++mi) {
          const int row = w * 32 + mi * 16 + m16;
          const int sw  = q ^ ((row >> 1) & 3);
          af[mi] = *(const bf16x8*)(ring + slot * 4096 + row * 32 + sw * 8);
        }
#pragma unroll
        for (int g = 0; g < 4; ++g)
          bfr[g] = *(const bf16x8*)(Bs + (g * 16 + m16) * KP + kc * 32 + q * 8);
        WAIT_LGKM0;                   // frags in regs; ring slot kc%3 free
        if (kc + 3 < nc) stage(kc + 3);
#pragma unroll
        for (int mi = 0; mi < 2; ++mi)
#pragma unroll
          for (int g = 0; g < 4; ++g)
            acc[mi][g] = __builtin_amdgcn_mfma_f32_16x16x32_bf16(af[mi], bfr[g], acc[mi][g], 0, 0, 0);
      }

      // in-register epilogue; coherent h stores
      __hip_bfloat16* hout = z2 ? ((ph & 1) ? p.h2b1 : p.h2b0)            // h2[ph]
                                : (((ph + 1) & 1) ? p.h1b1 : p.h1b0);     // h1[ph+1]
      const int j = ntile * 16 + m16;
#pragma unroll
      for (int mi = 0; mi < 2; ++mi)
#pragma unroll
        for (int rr = 0; rr < 4; ++rr) {
          const float zi = acc[mi][0][rr], zf = acc[mi][1][rr];
          const float zg = acc[mi][2][rr], zo = acc[mi][3][rr];
          const float cn = sigm(zf) * cst[mi][rr] + sigm(zi) * tanhp(zg);
          cst[mi][rr] = cn;
          const int row = m0 + w * 32 + mi * 16 + q * 4 + rr;
          coh_store_bf16(hout + (size_t)row * HDIM + j, sigm(zo) * tanhp(cn));
        }
    }

    // ---- per-group barrier: no cache maintenance, just LLC handshake ----
    WAIT_VM0;                         // h stores committed to LLC
    __syncthreads();
    if (tid == 0) {
      const unsigned int tgt = 64u * (unsigned)(ph + 2);
      if (atomicAdd(cnt, 1u) + 1u < tgt)
        while (coh_load(cnt) < tgt) __builtin_amdgcn_s_sleep(2);
    }
    __syncthreads();
  }

  // final FC: block b -> rows {2b, 2b+1}; wait on producer group's counter
  if (tid == 0) {
    unsigned int* pc = p.cnt + (blockIdx.x >> 6) * 32;
    while (coh_load(pc) < 64u * 81u) __builtin_amdgcn_s_sleep(2);
  }
  __syncthreads();
  if (w < 2) {
    const int row = blockIdx.x * 2 + w;
    const unsigned int* hp = (const unsigned int*)(p.h2b1 + (size_t)row * HDIM);
    float sum = 0.f;
#pragma unroll
    for (int c = 0; c < 4; ++c) {
      unsigned int d = coh_load(hp + lane * 4 + c);
      union { unsigned int ui; float f; } lo, hi;
      lo.ui = d << 16; hi.ui = d & 0xffff0000u;
      sum += lo.f * p.Wfc[(lane * 4 + c) * 2] + hi.f * p.Wfc[(lane * 4 + c) * 2 + 1];
    }
#pragma unroll
    for (int o = 32; o > 0; o >>= 1) sum += __shfl_down(sum, o, 64);
    if (lane == 0) p.out[row] = sigm(sum + p.bfc[0]);
  }
}

// ---------------- host launcher ----------------

extern "C" void kernel_launch(void* const* d_in, const int* in_sizes, int n_in,
                              void* d_out, int out_size, void* d_ws, size_t ws_size,
                              hipStream_t stream) {
  const int*   tokens = (const int*)d_in[0];
  const float* emb = (const float*)d_in[1];
  const float* W1  = (const float*)d_in[2];
  const float* U1  = (const float*)d_in[3];
  const float* b1  = (const float*)d_in[4];
  const float* W2  = (const float*)d_in[5];
  const float* U2  = (const float*)d_in[6];
  const float* b2  = (const float*)d_in[7];
  const float* Wfc = (const float*)d_in[8];
  const float* bfc = (const float*)d_in[9];

  char* ws = (char*)d_ws;
  size_t off = 0;
  auto alloc = [&](size_t bytes) {
    char* r = ws + off;
    off += (bytes + 255) & ~(size_t)255;
    return r;
  };
  __hip_bfloat16* Wz1t = (__hip_bfloat16*)alloc(2048UL * K1 * 2);
  __hip_bfloat16* Wz2t = (__hip_bfloat16*)alloc(2048UL * K2 * 2);
  float* bz1 = (float*)alloc(2048 * 4);
  float* bz2 = (float*)alloc(2048 * 4);
  __hip_bfloat16* Xall = (__hip_bfloat16*)alloc((size_t)TSTEPS * BATCH * EDIM * 2);
  char* state = alloc(2UL * 1024 * 1024 + 4096);   // 4 h-buffers + counters, zeroed
  __hip_bfloat16* h1b0 = (__hip_bfloat16*)(state);
  __hip_bfloat16* h1b1 = (__hip_bfloat16*)(state + 512 * 1024);
  __hip_bfloat16* h2b0 = (__hip_bfloat16*)(state + 1024 * 1024);
  __hip_bfloat16* h2b1 = (__hip_bfloat16*)(state + 1536 * 1024);
  unsigned int*   cnt  = (unsigned int*)(state + 2048 * 1024);

  prep_weights<<<dim3(14352), dim3(256), 0, stream>>>(W1, U1, b1, W2, U2, b2, Wz1t, Wz2t, bz1, bz2);
  prep_gather<<<dim3(10240), dim3(256), 0, stream>>>(tokens, emb, Xall);
  zero_ws<<<dim3(516), dim3(256), 0, stream>>>((float4*)state, 131328);

  hipFuncSetAttribute((const void*)lstm_seq,
                      hipFuncAttributeMaxDynamicSharedMemorySize, LDS_BYTES);

  Params prm;
  prm.Wz1t = Wz1t; prm.Wz2t = Wz2t; prm.bz1 = bz1; prm.bz2 = bz2;
  prm.Xall = Xall;
  prm.h1b0 = h1b0; prm.h1b1 = h1b1; prm.h2b0 = h2b0; prm.h2b1 = h2b1;
  prm.cnt = cnt;
  prm.Wfc = Wfc; prm.bfc = bfc;
  prm.out = (float*)d_out;

  void* args[] = {&prm};
  hipLaunchCooperativeKernel((const void*)lstm_seq, dim3(256), dim3(256), args, LDS_BYTES, stream);
}